// Round 10
// baseline (468.766 us; speedup 1.0000x reference)
//
#include <hip/hip_runtime.h>
#include <math.h>

#define N_NODES 100000
#define N_EDGES 1600000
#define HID 48
#define HPAD 64          // padded feature stride: 128 B = one cache line per node
#define ALPHA 0.1f

#define LBLK 3125        // layer grid: 4 waves/block, 8 nodes/wave = exactly 100000 nodes
#define NPW 8
#define FBLK 6250        // final grid: 4 waves/block, 4 nodes/wave
#define FNPW 4

#define CNT_BLK 3125     // count part: 2 edges/thread: 3125*256*2 = 1,600,000
#define LIN0_BLK 2344    // lin0 part: 2344*256 >= 600,000

typedef unsigned short u16;
typedef unsigned int u32;

__device__ __forceinline__ float bf_lo(u32 u) { return __uint_as_float(u << 16); }
__device__ __forceinline__ float bf_hi(u32 u) { return __uint_as_float(u & 0xffff0000u); }
__device__ __forceinline__ u16 f2bf(float f) {
    u32 b = __float_as_uint(f);
    b += 0x7fff + ((b >> 16) & 1);   // round-to-nearest-even
    return (u16)(b >> 16);
}
__device__ __forceinline__ u32 pack2(float a, float b) {
    return (u32)f2bf(a) | ((u32)f2bf(b) << 16);
}

// broadcast lane l's value (uniform, ignores exec); FMA consumes it as the scalar operand
#define RLANE(x, l) __int_as_float(__builtin_amdgcn_readlane(__float_as_int(x), (l)))

// ---------------- fused: count (ret-atomic rank) + lin0 ----------------
// The count part is atomic-wall-bound with CUs ~99.5% idle; lin0's BW/VALU work
// rides on the idle CUs for free (heterogeneous blocks, no dependency).
__global__ __launch_bounds__(256) void cl_k(const int* __restrict__ dst, int* __restrict__ deg,
                                            int* __restrict__ rank,
                                            const float* __restrict__ x, const float* __restrict__ W0,
                                            const float* __restrict__ b0, u16* __restrict__ h0) {
    int b = blockIdx.x;
    if (b < CNT_BLK) {
        int e = (b * 256 + threadIdx.x) * 2;
        int2 d2 = *(const int2*)(dst + e);
        int r0 = atomicAdd(&deg[d2.x], 1);
        int r1 = atomicAdd(&deg[d2.y], 1);
        *(int2*)(rank + e) = make_int2(r0, r1);
    } else {
        int t = (b - CNT_BLK) * 256 + threadIdx.x;
        if (t >= N_NODES * 6) return;
        int node = t / 6, oct = t % 6;
        float xv0 = x[node * 3 + 0], xv1 = x[node * 3 + 1], xv2 = x[node * 3 + 2];
        float v[8];
#pragma unroll
        for (int j = 0; j < 8; j++) {
            int f = oct * 8 + j;
            float s = b0[f] + xv0 * W0[0 * HID + f] + xv1 * W0[1 * HID + f] + xv2 * W0[2 * HID + f];
            v[j] = s > 0.f ? s : 0.f;
        }
        uint4 p;
        p.x = pack2(v[0], v[1]); p.y = pack2(v[2], v[3]);
        p.z = pack2(v[4], v[5]); p.w = pack2(v[6], v[7]);
        *(uint4*)(h0 + (size_t)node * HPAD + oct * 8) = p;
    }
}

// ---------------- CSR build (scan + scatter) ----------------
__global__ __launch_bounds__(256) void scan1_k(const int* __restrict__ deg, int* __restrict__ rowptr,
                                               int* __restrict__ partial) {
    __shared__ int sums[256];
    int tid = threadIdx.x;
    int base = blockIdx.x * 2048 + tid * 8;
    int v[8]; int s = 0;
#pragma unroll
    for (int j = 0; j < 8; j++) { int idx = base + j; v[j] = (idx < N_NODES) ? deg[idx] : 0; s += v[j]; }
    sums[tid] = s; __syncthreads();
    for (int off = 1; off < 256; off <<= 1) {
        int t = (tid >= off) ? sums[tid - off] : 0;
        __syncthreads();
        sums[tid] += t;
        __syncthreads();
    }
    if (tid == 255) partial[blockIdx.x] = sums[255];
    int run = (tid > 0) ? sums[tid - 1] : 0;
#pragma unroll
    for (int j = 0; j < 8; j++) { int idx = base + j; if (idx < N_NODES) rowptr[idx] = run; run += v[j]; }
}

__global__ void scan2_k(int* __restrict__ partial, int* __restrict__ rowptr, int nblk) {
    int lane = threadIdx.x & 63;
    int v = (lane < nblk) ? partial[lane] : 0;
    for (int off = 1; off < 64; off <<= 1) {
        int t = __shfl_up(v, off);
        if (lane >= off) v += t;
    }
    int excl = __shfl_up(v, 1);
    if (lane == 0) excl = 0;
    if (lane < nblk) partial[lane] = excl;
    if (lane == 63) rowptr[N_NODES] = v;
}

__global__ __launch_bounds__(256) void scan3_k(int* __restrict__ rowptr, const int* __restrict__ partial) {
    int tid = threadIdx.x;
    int base = blockIdx.x * 2048 + tid * 8;
    int add = partial[blockIdx.x];
#pragma unroll
    for (int j = 0; j < 8; j++) {
        int idx = base + j;
        if (idx < N_NODES) rowptr[idx] += add;
    }
}

// atomic-free scatter: position = rowptr[dst] + rank. Non-temporal store bypasses the
// 8 non-coherent XCD L2s (which each write-allocate + write back PARTIAL lines of the
// same 64B line -> the measured ~16x write amplification); pieces merge memory-side.
__global__ __launch_bounds__(256) void bucket_k(const int* __restrict__ src, const int* __restrict__ dst,
                                                const int* __restrict__ rank, const int* __restrict__ rowptr,
                                                int* __restrict__ ssrc) {
    int e = blockIdx.x * 256 + threadIdx.x;
    if (e < N_EDGES) {
        int d = dst[e];
        int s = src[e];
        __builtin_nontemporal_store(s, ssrc + rowptr[d] + rank[e]);
    }
}

// ---------------- fused layer: depth-3 node pipeline, 8 nodes/wave ----------------
// slot = lane>>3 (edge within octet), chunk = lane&7 (feature octet, 6 active).
// Prefetch(node) = rowptr + 3 predicated ssrc loads + 3 uint4 gathers (24 edges,
// covers 98.3% of Poisson(16) degrees). Loads stay TWO nodes ahead of process:
// a node's ~700cy ssrc->gather chain hides under two nodes' compute.
struct PF { int e0, e1; uint4 wA, wB, wC; };

__device__ __forceinline__ PF pf_load(const u16* __restrict__ h_in, const int* __restrict__ rowptr,
                                      const int* __restrict__ ssrc, int node, int slot, int cc) {
    PF p;
    p.e0 = rowptr[node];
    p.e1 = rowptr[node + 1];
    int es = p.e0 < N_EDGES ? p.e0 : N_EDGES - 1;   // safe clamp (empty trailing rows)
    int iA = p.e0 + slot, iB = p.e0 + 8 + slot, iC = p.e0 + 16 + slot;
    int sA = ssrc[iA < p.e1 ? iA : es];
    int sB = ssrc[iB < p.e1 ? iB : es];
    int sC = ssrc[iC < p.e1 ? iC : es];
    p.wA = *(const uint4*)(h_in + ((size_t)sA << 6) + cc * 8);
    p.wB = *(const uint4*)(h_in + ((size_t)sB << 6) + cc * 8);
    p.wC = *(const uint4*)(h_in + ((size_t)sC << 6) + cc * 8);
    return p;
}

__device__ __forceinline__ void acc8(float& a0, float& a1, float& a2, float& a3,
                                     float& a4, float& a5, float& a6, float& a7, const uint4& w) {
    a0 += bf_lo(w.x); a1 += bf_hi(w.x);
    a2 += bf_lo(w.y); a3 += bf_hi(w.y);
    a4 += bf_lo(w.z); a5 += bf_hi(w.z);
    a6 += bf_lo(w.w); a7 += bf_hi(w.w);
}

__device__ __forceinline__ void process_node(const PF& p, int node, int slot, int cc, int lane,
                                             const float (&wreg)[48],
                                             const u16* __restrict__ h_in, const u16* __restrict__ x0,
                                             const int* __restrict__ ssrc, u16* __restrict__ h_out) {
    // residual load issues first: overlaps the unpack/reduce below
    const uint4 xv = *(const uint4*)(x0 + ((size_t)node << 6) + cc * 8);
    float a0 = 0.f, a1 = 0.f, a2 = 0.f, a3 = 0.f, a4 = 0.f, a5 = 0.f, a6 = 0.f, a7 = 0.f;
    int e0 = p.e0, e1 = p.e1;
    if (e0 + slot < e1)      acc8(a0, a1, a2, a3, a4, a5, a6, a7, p.wA);
    if (e0 + 8 + slot < e1)  acc8(a0, a1, a2, a3, a4, a5, a6, a7, p.wB);
    if (e0 + 16 + slot < e1) acc8(a0, a1, a2, a3, a4, a5, a6, a7, p.wC);
    // overflow path for deg > 24 (rare: ~1.7% of nodes)
    for (int e = e0 + 24; e < e1; e += 8) {
        int idx = e + slot;
        int s = ssrc[idx < e1 ? idx : e];   // e < e1 here, ssrc[e] is a safe address
        const uint4 w = *(const uint4*)(h_in + ((size_t)s << 6) + cc * 8);
        if (idx < e1) acc8(a0, a1, a2, a3, a4, a5, a6, a7, w);
    }
    // rejoin 8 slot partials (lane bits 3,4,5)
#pragma unroll
    for (int off = 8; off <= 32; off <<= 1) {
        a0 += __shfl_xor(a0, off); a1 += __shfl_xor(a1, off);
        a2 += __shfl_xor(a2, off); a3 += __shfl_xor(a3, off);
        a4 += __shfl_xor(a4, off); a5 += __shfl_xor(a5, off);
        a6 += __shfl_xor(a6, off); a7 += __shfl_xor(a7, off);
    }
    a0 = (1.f - ALPHA) * a0 + ALPHA * bf_lo(xv.x);
    a1 = (1.f - ALPHA) * a1 + ALPHA * bf_hi(xv.x);
    a2 = (1.f - ALPHA) * a2 + ALPHA * bf_lo(xv.y);
    a3 = (1.f - ALPHA) * a3 + ALPHA * bf_hi(xv.y);
    a4 = (1.f - ALPHA) * a4 + ALPHA * bf_lo(xv.z);
    a5 = (1.f - ALPHA) * a5 + ALPHA * bf_hi(xv.z);
    a6 = (1.f - ALPHA) * a6 + ALPHA * bf_lo(xv.w);
    a7 = (1.f - ALPHA) * a7 + ALPHA * bf_hi(xv.w);
    // o[f] = sum_r t[r]*M[r][f]; t[c*8+j] lives in a_j of lane c (c=0..5)
    float p0 = 0.f, p1 = 0.f, p2 = 0.f, p3 = 0.f;
#pragma unroll
    for (int c = 0; c < 6; ++c) {
        p0 = fmaf(RLANE(a0, c), wreg[c * 8 + 0], p0);
        p1 = fmaf(RLANE(a1, c), wreg[c * 8 + 1], p1);
        p2 = fmaf(RLANE(a2, c), wreg[c * 8 + 2], p2);
        p3 = fmaf(RLANE(a3, c), wreg[c * 8 + 3], p3);
        p0 = fmaf(RLANE(a4, c), wreg[c * 8 + 4], p0);
        p1 = fmaf(RLANE(a5, c), wreg[c * 8 + 5], p1);
        p2 = fmaf(RLANE(a6, c), wreg[c * 8 + 6], p2);
        p3 = fmaf(RLANE(a7, c), wreg[c * 8 + 7], p3);
    }
    float o = (p0 + p1) + (p2 + p3);
    if (lane < 48) h_out[((size_t)node << 6) + lane] = f2bf(o > 0.f ? o : 0.f);
}

__global__ __launch_bounds__(256) void layer_k(const u16* __restrict__ h_in, const u16* __restrict__ x0,
                                               const int* __restrict__ rowptr, const int* __restrict__ ssrc,
                                               const float* __restrict__ W, float beta,
                                               u16* __restrict__ h_out) {
    __shared__ float sM[2304];
    int tid = threadIdx.x, lane = tid & 63;
    for (int i = tid; i < 2304; i += 256) {
        int r = i / 48, c = i - r * 48;
        float v = beta * W[i];
        if (r == c) v += 1.f - beta;
        sM[i] = v;
    }
    __syncthreads();
    int f = lane < 48 ? lane : 0;
    float wreg[48];
#pragma unroll
    for (int r = 0; r < 48; ++r) wreg[r] = sM[r * 48 + f];   // lane-stride-1, conflict-free, once/wave

    int chunk = lane & 7;
    int slot  = lane >> 3;
    int cc = chunk < 6 ? chunk : 0;
    int wid = __builtin_amdgcn_readfirstlane(blockIdx.x * 4 + (tid >> 6));
    int base = wid * NPW;   // LBLK*4*NPW == N_NODES exactly: no bounds checks

    // depth-3 rotating pipeline over 8 nodes (static names, no dynamic indexing):
    // loads stay 2 nodes ahead of process
    PF A = pf_load(h_in, rowptr, ssrc, base + 0, slot, cc);
    PF B = pf_load(h_in, rowptr, ssrc, base + 1, slot, cc);
    PF C = pf_load(h_in, rowptr, ssrc, base + 2, slot, cc);
    process_node(A, base + 0, slot, cc, lane, wreg, h_in, x0, ssrc, h_out);
    A = pf_load(h_in, rowptr, ssrc, base + 3, slot, cc);
    process_node(B, base + 1, slot, cc, lane, wreg, h_in, x0, ssrc, h_out);
    B = pf_load(h_in, rowptr, ssrc, base + 4, slot, cc);
    process_node(C, base + 2, slot, cc, lane, wreg, h_in, x0, ssrc, h_out);
    C = pf_load(h_in, rowptr, ssrc, base + 5, slot, cc);
    process_node(A, base + 3, slot, cc, lane, wreg, h_in, x0, ssrc, h_out);
    A = pf_load(h_in, rowptr, ssrc, base + 6, slot, cc);
    process_node(B, base + 4, slot, cc, lane, wreg, h_in, x0, ssrc, h_out);
    B = pf_load(h_in, rowptr, ssrc, base + 7, slot, cc);
    process_node(C, base + 5, slot, cc, lane, wreg, h_in, x0, ssrc, h_out);
    process_node(A, base + 6, slot, cc, lane, wreg, h_in, x0, ssrc, h_out);
    process_node(B, base + 7, slot, cc, lane, wreg, h_in, x0, ssrc, h_out);
}

// ---------------- final: out = log_softmax(h @ W1 + b1) ----------------
__global__ __launch_bounds__(256) void final_k(const u16* __restrict__ h, const float* __restrict__ W1,
                                               const float* __restrict__ b1, float* __restrict__ out) {
    __shared__ float sW[2304];
    int tid = threadIdx.x, lane = tid & 63;
    for (int i = tid; i < 2304; i += 256) sW[i] = W1[i];
    __syncthreads();
    int f = lane < 48 ? lane : 0;
    float wreg[48];
#pragma unroll
    for (int r = 0; r < 48; ++r) wreg[r] = sW[r * 48 + f];
    float bv = b1[f];
    int chunk = lane & 7;
    int cc = chunk < 6 ? chunk : 0;
    int wid = blockIdx.x * 4 + (tid >> 6);

    for (int i = 0; i < FNPW; ++i) {
        int node = wid * FNPW + i;
        if (node >= N_NODES) break;
        const uint4 hv = *(const uint4*)(h + ((size_t)node << 6) + cc * 8);
        float a0 = bf_lo(hv.x), a1 = bf_hi(hv.x), a2 = bf_lo(hv.y), a3 = bf_hi(hv.y);
        float a4 = bf_lo(hv.z), a5 = bf_hi(hv.z), a6 = bf_lo(hv.w), a7 = bf_hi(hv.w);
        float p0 = bv, p1 = 0.f, p2 = 0.f, p3 = 0.f;
#pragma unroll
        for (int c = 0; c < 6; ++c) {
            p0 = fmaf(RLANE(a0, c), wreg[c * 8 + 0], p0);
            p1 = fmaf(RLANE(a1, c), wreg[c * 8 + 1], p1);
            p2 = fmaf(RLANE(a2, c), wreg[c * 8 + 2], p2);
            p3 = fmaf(RLANE(a3, c), wreg[c * 8 + 3], p3);
            p0 = fmaf(RLANE(a4, c), wreg[c * 8 + 4], p0);
            p1 = fmaf(RLANE(a5, c), wreg[c * 8 + 5], p1);
            p2 = fmaf(RLANE(a6, c), wreg[c * 8 + 6], p2);
            p3 = fmaf(RLANE(a7, c), wreg[c * 8 + 7], p3);
        }
        float v = (lane < 48) ? (p0 + p1) + (p2 + p3) : -INFINITY;
        float m = v;
        for (int off = 32; off >= 1; off >>= 1) m = fmaxf(m, __shfl_xor(m, off));
        float ex = (lane < 48) ? expf(v - m) : 0.f;
        float sum = ex;
        for (int off = 32; off >= 1; off >>= 1) sum += __shfl_xor(sum, off);
        if (lane < 48) out[(size_t)node * 48 + lane] = v - m - logf(sum);
    }
}

extern "C" void kernel_launch(void* const* d_in, const int* in_sizes, int n_in,
                              void* d_out, int out_size, void* d_ws, size_t ws_size,
                              hipStream_t stream) {
    const float* x     = (const float*)d_in[0];
    const int*   ei    = (const int*)d_in[1];
    const float* W0    = (const float*)d_in[2];
    const float* b0    = (const float*)d_in[3];
    const float* convW = (const float*)d_in[4];
    const float* W1    = (const float*)d_in[5];
    const float* b1    = (const float*)d_in[6];
    float* out = (float*)d_out;
    const int* src = ei;            // edge_index[0]
    const int* dst = ei + N_EDGES;  // edge_index[1]

    char* ws = (char*)d_ws;
    size_t off = 0;
    u16* h0 = (u16*)(ws + off); off += (size_t)N_NODES * HPAD * 2;   // 12.8 MB bf16, preserved residual (x0 == h0)
    u16* hA = (u16*)(ws + off); off += (size_t)N_NODES * HPAD * 2;   // 12.8 MB
    u16* hB = (u16*)(ws + off); off += (size_t)N_NODES * HPAD * 2;   // 12.8 MB
    int* rank = (int*)hA;           // alias: rank (6.4 MB) dead after bucket_k; hA first written by layer 2
    int* ssrc = (int*)(ws + off);   off += (size_t)N_EDGES * 4;      // 6.4 MB
    int* rowptr = (int*)(ws + off); off += (size_t)(N_NODES + 1) * 4;
    off = (off + 255) & ~(size_t)255;
    int* deg = (int*)(ws + off);    off += (size_t)N_NODES * 4;
    off = (off + 255) & ~(size_t)255;
    int* partial = (int*)(ws + off); off += 64 * 4;

    hipMemsetAsync(deg, 0, (size_t)N_NODES * 4, stream);

    // fused count(2 edges/thread) + lin0: lin0 rides the idle CUs of the atomic wall
    cl_k<<<CNT_BLK + LIN0_BLK, 256, 0, stream>>>(dst, deg, rank, x, W0, b0, h0);
    scan1_k<<<49, 256, 0, stream>>>(deg, rowptr, partial);
    scan2_k<<<1, 64, 0, stream>>>(partial, rowptr, 49);
    scan3_k<<<49, 256, 0, stream>>>(rowptr, partial);
    bucket_k<<<6250, 256, 0, stream>>>(src, dst, rank, rowptr, ssrc);

    const float betas[4] = { logf(1.5f), logf(1.25f), logf(7.f / 6.f), logf(1.125f) };

    // x0 residual = h0 (same values); h0 preserved, hA/hB ping-pong
    layer_k<<<LBLK, 256, 0, stream>>>(h0, h0, rowptr, ssrc, convW + 0 * 2304, betas[0], hB);
    layer_k<<<LBLK, 256, 0, stream>>>(hB, h0, rowptr, ssrc, convW + 1 * 2304, betas[1], hA);
    layer_k<<<LBLK, 256, 0, stream>>>(hA, h0, rowptr, ssrc, convW + 2 * 2304, betas[2], hB);
    layer_k<<<LBLK, 256, 0, stream>>>(hB, h0, rowptr, ssrc, convW + 3 * 2304, betas[3], hA);
    final_k<<<FBLK, 256, 0, stream>>>(hA, W1, b1, out);
}

// Round 11
// 441.469 us; speedup vs baseline: 1.0618x; 1.0618x over previous
//
#include <hip/hip_runtime.h>
#include <math.h>

#define N_NODES 100000
#define N_EDGES 1600000
#define HID 48
#define HPAD 64          // padded feature stride: 128 B = one cache line per node
#define ALPHA 0.1f

#define LBLK 6250        // layer grid: 4 waves/block, 4 nodes/wave = exactly 100000 nodes
#define NPW 4

#define CNT_BLK 3125     // count part: 2 edges/thread: 3125*256*2 = 1,600,000
#define LIN0_BLK 2344    // lin0 part: 2344*256 >= 600,000

typedef unsigned short u16;
typedef unsigned int u32;

__device__ __forceinline__ float bf_lo(u32 u) { return __uint_as_float(u << 16); }
__device__ __forceinline__ float bf_hi(u32 u) { return __uint_as_float(u & 0xffff0000u); }
__device__ __forceinline__ u16 f2bf(float f) {
    u32 b = __float_as_uint(f);
    b += 0x7fff + ((b >> 16) & 1);   // round-to-nearest-even
    return (u16)(b >> 16);
}
__device__ __forceinline__ u32 pack2(float a, float b) {
    return (u32)f2bf(a) | ((u32)f2bf(b) << 16);
}

// broadcast lane l's value (uniform, ignores exec); FMA consumes it as the scalar operand
#define RLANE(x, l) __int_as_float(__builtin_amdgcn_readlane(__float_as_int(x), (l)))

// ---------------- fused: count (ret-atomic rank) + lin0 ----------------
// The count part is atomic-wall-bound with CUs ~99.5% idle; lin0's BW/VALU work
// rides on the idle CUs (measured: 80us serial -> 72.8us fused, R10).
__global__ __launch_bounds__(256) void cl_k(const int* __restrict__ dst, int* __restrict__ deg,
                                            int* __restrict__ rank,
                                            const float* __restrict__ x, const float* __restrict__ W0,
                                            const float* __restrict__ b0, u16* __restrict__ h0) {
    int b = blockIdx.x;
    if (b < CNT_BLK) {
        int e = (b * 256 + threadIdx.x) * 2;
        int2 d2 = *(const int2*)(dst + e);
        int r0 = atomicAdd(&deg[d2.x], 1);
        int r1 = atomicAdd(&deg[d2.y], 1);
        *(int2*)(rank + e) = make_int2(r0, r1);
    } else {
        int t = (b - CNT_BLK) * 256 + threadIdx.x;
        if (t >= N_NODES * 6) return;
        int node = t / 6, oct = t % 6;
        float xv0 = x[node * 3 + 0], xv1 = x[node * 3 + 1], xv2 = x[node * 3 + 2];
        float v[8];
#pragma unroll
        for (int j = 0; j < 8; j++) {
            int f = oct * 8 + j;
            float s = b0[f] + xv0 * W0[0 * HID + f] + xv1 * W0[1 * HID + f] + xv2 * W0[2 * HID + f];
            v[j] = s > 0.f ? s : 0.f;
        }
        uint4 p;
        p.x = pack2(v[0], v[1]); p.y = pack2(v[2], v[3]);
        p.z = pack2(v[4], v[5]); p.w = pack2(v[6], v[7]);
        *(uint4*)(h0 + (size_t)node * HPAD + oct * 8) = p;
    }
}

// ---------------- CSR build (scan + scatter) ----------------
__global__ __launch_bounds__(256) void scan1_k(const int* __restrict__ deg, int* __restrict__ rowptr,
                                               int* __restrict__ partial) {
    __shared__ int sums[256];
    int tid = threadIdx.x;
    int base = blockIdx.x * 2048 + tid * 8;
    int v[8]; int s = 0;
#pragma unroll
    for (int j = 0; j < 8; j++) { int idx = base + j; v[j] = (idx < N_NODES) ? deg[idx] : 0; s += v[j]; }
    sums[tid] = s; __syncthreads();
    for (int off = 1; off < 256; off <<= 1) {
        int t = (tid >= off) ? sums[tid - off] : 0;
        __syncthreads();
        sums[tid] += t;
        __syncthreads();
    }
    if (tid == 255) partial[blockIdx.x] = sums[255];
    int run = (tid > 0) ? sums[tid - 1] : 0;
#pragma unroll
    for (int j = 0; j < 8; j++) { int idx = base + j; if (idx < N_NODES) rowptr[idx] = run; run += v[j]; }
}

__global__ void scan2_k(int* __restrict__ partial, int* __restrict__ rowptr, int nblk) {
    int lane = threadIdx.x & 63;
    int v = (lane < nblk) ? partial[lane] : 0;
    for (int off = 1; off < 64; off <<= 1) {
        int t = __shfl_up(v, off);
        if (lane >= off) v += t;
    }
    int excl = __shfl_up(v, 1);
    if (lane == 0) excl = 0;
    if (lane < nblk) partial[lane] = excl;
    if (lane == 63) rowptr[N_NODES] = v;
}

__global__ __launch_bounds__(256) void scan3_k(int* __restrict__ rowptr, const int* __restrict__ partial) {
    int tid = threadIdx.x;
    int base = blockIdx.x * 2048 + tid * 8;
    int add = partial[blockIdx.x];
#pragma unroll
    for (int j = 0; j < 8; j++) {
        int idx = base + j;
        if (idx < N_NODES) rowptr[idx] += add;
    }
}

// atomic-free scatter: position = rowptr[dst] + rank. Plain store (R10's NT store
// was one of two suspects in a +23us regression; reverted to the measured-good path).
__global__ __launch_bounds__(256) void bucket_k(const int* __restrict__ src, const int* __restrict__ dst,
                                                const int* __restrict__ rank, const int* __restrict__ rowptr,
                                                int* __restrict__ ssrc) {
    int e = blockIdx.x * 256 + threadIdx.x;
    if (e < N_EDGES) {
        int d = dst[e];
        ssrc[rowptr[d] + rank[e]] = src[e];
    }
}

// ---------------- fused layer: depth-2 node pipeline (R9-proven, ~66us/layer) ----------------
struct PF { int e0, e1; uint4 wA, wB, wC; };

__device__ __forceinline__ PF pf_load(const u16* __restrict__ h_in, const int* __restrict__ rowptr,
                                      const int* __restrict__ ssrc, int node, int slot, int cc) {
    PF p;
    p.e0 = rowptr[node];
    p.e1 = rowptr[node + 1];
    int es = p.e0 < N_EDGES ? p.e0 : N_EDGES - 1;   // safe clamp (empty trailing rows)
    int iA = p.e0 + slot, iB = p.e0 + 8 + slot, iC = p.e0 + 16 + slot;
    int sA = ssrc[iA < p.e1 ? iA : es];
    int sB = ssrc[iB < p.e1 ? iB : es];
    int sC = ssrc[iC < p.e1 ? iC : es];
    p.wA = *(const uint4*)(h_in + ((size_t)sA << 6) + cc * 8);
    p.wB = *(const uint4*)(h_in + ((size_t)sB << 6) + cc * 8);
    p.wC = *(const uint4*)(h_in + ((size_t)sC << 6) + cc * 8);
    return p;
}

__device__ __forceinline__ void acc8(float& a0, float& a1, float& a2, float& a3,
                                     float& a4, float& a5, float& a6, float& a7, const uint4& w) {
    a0 += bf_lo(w.x); a1 += bf_hi(w.x);
    a2 += bf_lo(w.y); a3 += bf_hi(w.y);
    a4 += bf_lo(w.z); a5 += bf_hi(w.z);
    a6 += bf_lo(w.w); a7 += bf_hi(w.w);
}

__device__ __forceinline__ void process_node(const PF& p, int node, int slot, int cc, int lane,
                                             const float (&wreg)[48],
                                             const u16* __restrict__ h_in, const u16* __restrict__ x0,
                                             const int* __restrict__ ssrc, u16* __restrict__ h_out) {
    // residual load issues first: overlaps the unpack/reduce below
    const uint4 xv = *(const uint4*)(x0 + ((size_t)node << 6) + cc * 8);
    float a0 = 0.f, a1 = 0.f, a2 = 0.f, a3 = 0.f, a4 = 0.f, a5 = 0.f, a6 = 0.f, a7 = 0.f;
    int e0 = p.e0, e1 = p.e1;
    if (e0 + slot < e1)      acc8(a0, a1, a2, a3, a4, a5, a6, a7, p.wA);
    if (e0 + 8 + slot < e1)  acc8(a0, a1, a2, a3, a4, a5, a6, a7, p.wB);
    if (e0 + 16 + slot < e1) acc8(a0, a1, a2, a3, a4, a5, a6, a7, p.wC);
    // overflow path for deg > 24 (rare: ~1.7% of nodes)
    for (int e = e0 + 24; e < e1; e += 8) {
        int idx = e + slot;
        int s = ssrc[idx < e1 ? idx : e];   // e < e1 here, ssrc[e] is a safe address
        const uint4 w = *(const uint4*)(h_in + ((size_t)s << 6) + cc * 8);
        if (idx < e1) acc8(a0, a1, a2, a3, a4, a5, a6, a7, w);
    }
    // rejoin 8 slot partials (lane bits 3,4,5)
#pragma unroll
    for (int off = 8; off <= 32; off <<= 1) {
        a0 += __shfl_xor(a0, off); a1 += __shfl_xor(a1, off);
        a2 += __shfl_xor(a2, off); a3 += __shfl_xor(a3, off);
        a4 += __shfl_xor(a4, off); a5 += __shfl_xor(a5, off);
        a6 += __shfl_xor(a6, off); a7 += __shfl_xor(a7, off);
    }
    a0 = (1.f - ALPHA) * a0 + ALPHA * bf_lo(xv.x);
    a1 = (1.f - ALPHA) * a1 + ALPHA * bf_hi(xv.x);
    a2 = (1.f - ALPHA) * a2 + ALPHA * bf_lo(xv.y);
    a3 = (1.f - ALPHA) * a3 + ALPHA * bf_hi(xv.y);
    a4 = (1.f - ALPHA) * a4 + ALPHA * bf_lo(xv.z);
    a5 = (1.f - ALPHA) * a5 + ALPHA * bf_hi(xv.z);
    a6 = (1.f - ALPHA) * a6 + ALPHA * bf_lo(xv.w);
    a7 = (1.f - ALPHA) * a7 + ALPHA * bf_hi(xv.w);
    // o[f] = sum_r t[r]*M[r][f]; t[c*8+j] lives in a_j of lane c (c=0..5)
    float p0 = 0.f, p1 = 0.f, p2 = 0.f, p3 = 0.f;
#pragma unroll
    for (int c = 0; c < 6; ++c) {
        p0 = fmaf(RLANE(a0, c), wreg[c * 8 + 0], p0);
        p1 = fmaf(RLANE(a1, c), wreg[c * 8 + 1], p1);
        p2 = fmaf(RLANE(a2, c), wreg[c * 8 + 2], p2);
        p3 = fmaf(RLANE(a3, c), wreg[c * 8 + 3], p3);
        p0 = fmaf(RLANE(a4, c), wreg[c * 8 + 4], p0);
        p1 = fmaf(RLANE(a5, c), wreg[c * 8 + 5], p1);
        p2 = fmaf(RLANE(a6, c), wreg[c * 8 + 6], p2);
        p3 = fmaf(RLANE(a7, c), wreg[c * 8 + 7], p3);
    }
    float o = (p0 + p1) + (p2 + p3);
    if (lane < 48) h_out[((size_t)node << 6) + lane] = f2bf(o > 0.f ? o : 0.f);
}

__global__ __launch_bounds__(256) void layer_k(const u16* __restrict__ h_in, const u16* __restrict__ x0,
                                               const int* __restrict__ rowptr, const int* __restrict__ ssrc,
                                               const float* __restrict__ W, float beta,
                                               u16* __restrict__ h_out) {
    __shared__ float sM[2304];
    int tid = threadIdx.x, lane = tid & 63;
    for (int i = tid; i < 2304; i += 256) {
        int r = i / 48, c = i - r * 48;
        float v = beta * W[i];
        if (r == c) v += 1.f - beta;
        sM[i] = v;
    }
    __syncthreads();
    int f = lane < 48 ? lane : 0;
    float wreg[48];
#pragma unroll
    for (int r = 0; r < 48; ++r) wreg[r] = sM[r * 48 + f];   // lane-stride-1, conflict-free, once/wave

    int chunk = lane & 7;
    int slot  = lane >> 3;
    int cc = chunk < 6 ? chunk : 0;
    int wid = __builtin_amdgcn_readfirstlane(blockIdx.x * 4 + (tid >> 6));
    int base = wid * NPW;   // LBLK*4*NPW == N_NODES exactly: no bounds checks

    // depth-2 software pipeline over 4 nodes (static names, no dynamic indexing)
    PF pA = pf_load(h_in, rowptr, ssrc, base + 0, slot, cc);
    PF pB = pf_load(h_in, rowptr, ssrc, base + 1, slot, cc);
    process_node(pA, base + 0, slot, cc, lane, wreg, h_in, x0, ssrc, h_out);
    PF pC = pf_load(h_in, rowptr, ssrc, base + 2, slot, cc);
    process_node(pB, base + 1, slot, cc, lane, wreg, h_in, x0, ssrc, h_out);
    PF pD = pf_load(h_in, rowptr, ssrc, base + 3, slot, cc);
    process_node(pC, base + 2, slot, cc, lane, wreg, h_in, x0, ssrc, h_out);
    process_node(pD, base + 3, slot, cc, lane, wreg, h_in, x0, ssrc, h_out);
}

// ---------------- final: out = log_softmax(h @ W1 + b1) ----------------
__global__ __launch_bounds__(256) void final_k(const u16* __restrict__ h, const float* __restrict__ W1,
                                               const float* __restrict__ b1, float* __restrict__ out) {
    __shared__ float sW[2304];
    int tid = threadIdx.x, lane = tid & 63;
    for (int i = tid; i < 2304; i += 256) sW[i] = W1[i];
    __syncthreads();
    int f = lane < 48 ? lane : 0;
    float wreg[48];
#pragma unroll
    for (int r = 0; r < 48; ++r) wreg[r] = sW[r * 48 + f];
    float bv = b1[f];
    int chunk = lane & 7;
    int cc = chunk < 6 ? chunk : 0;
    int wid = blockIdx.x * 4 + (tid >> 6);

    for (int i = 0; i < NPW; ++i) {
        int node = wid * NPW + i;
        if (node >= N_NODES) break;
        const uint4 hv = *(const uint4*)(h + ((size_t)node << 6) + cc * 8);
        float a0 = bf_lo(hv.x), a1 = bf_hi(hv.x), a2 = bf_lo(hv.y), a3 = bf_hi(hv.y);
        float a4 = bf_lo(hv.z), a5 = bf_hi(hv.z), a6 = bf_lo(hv.w), a7 = bf_hi(hv.w);
        float p0 = bv, p1 = 0.f, p2 = 0.f, p3 = 0.f;
#pragma unroll
        for (int c = 0; c < 6; ++c) {
            p0 = fmaf(RLANE(a0, c), wreg[c * 8 + 0], p0);
            p1 = fmaf(RLANE(a1, c), wreg[c * 8 + 1], p1);
            p2 = fmaf(RLANE(a2, c), wreg[c * 8 + 2], p2);
            p3 = fmaf(RLANE(a3, c), wreg[c * 8 + 3], p3);
            p0 = fmaf(RLANE(a4, c), wreg[c * 8 + 4], p0);
            p1 = fmaf(RLANE(a5, c), wreg[c * 8 + 5], p1);
            p2 = fmaf(RLANE(a6, c), wreg[c * 8 + 6], p2);
            p3 = fmaf(RLANE(a7, c), wreg[c * 8 + 7], p3);
        }
        float v = (lane < 48) ? (p0 + p1) + (p2 + p3) : -INFINITY;
        float m = v;
        for (int off = 32; off >= 1; off >>= 1) m = fmaxf(m, __shfl_xor(m, off));
        float ex = (lane < 48) ? expf(v - m) : 0.f;
        float sum = ex;
        for (int off = 32; off >= 1; off >>= 1) sum += __shfl_xor(sum, off);
        if (lane < 48) out[(size_t)node * 48 + lane] = v - m - logf(sum);
    }
}

extern "C" void kernel_launch(void* const* d_in, const int* in_sizes, int n_in,
                              void* d_out, int out_size, void* d_ws, size_t ws_size,
                              hipStream_t stream) {
    const float* x     = (const float*)d_in[0];
    const int*   ei    = (const int*)d_in[1];
    const float* W0    = (const float*)d_in[2];
    const float* b0    = (const float*)d_in[3];
    const float* convW = (const float*)d_in[4];
    const float* W1    = (const float*)d_in[5];
    const float* b1    = (const float*)d_in[6];
    float* out = (float*)d_out;
    const int* src = ei;            // edge_index[0]
    const int* dst = ei + N_EDGES;  // edge_index[1]

    char* ws = (char*)d_ws;
    size_t off = 0;
    u16* h0 = (u16*)(ws + off); off += (size_t)N_NODES * HPAD * 2;   // 12.8 MB bf16, preserved residual (x0 == h0)
    u16* hA = (u16*)(ws + off); off += (size_t)N_NODES * HPAD * 2;   // 12.8 MB
    u16* hB = (u16*)(ws + off); off += (size_t)N_NODES * HPAD * 2;   // 12.8 MB
    int* rank = (int*)hA;           // alias: rank (6.4 MB) dead after bucket_k; hA first written by layer 2
    int* ssrc = (int*)(ws + off);   off += (size_t)N_EDGES * 4;      // 6.4 MB
    int* rowptr = (int*)(ws + off); off += (size_t)(N_NODES + 1) * 4;
    off = (off + 255) & ~(size_t)255;
    int* deg = (int*)(ws + off);    off += (size_t)N_NODES * 4;
    off = (off + 255) & ~(size_t)255;
    int* partial = (int*)(ws + off); off += 64 * 4;

    hipMemsetAsync(deg, 0, (size_t)N_NODES * 4, stream);

    // fused count(2 edges/thread) + lin0: lin0 rides the idle CUs of the atomic wall
    cl_k<<<CNT_BLK + LIN0_BLK, 256, 0, stream>>>(dst, deg, rank, x, W0, b0, h0);
    scan1_k<<<49, 256, 0, stream>>>(deg, rowptr, partial);
    scan2_k<<<1, 64, 0, stream>>>(partial, rowptr, 49);
    scan3_k<<<49, 256, 0, stream>>>(rowptr, partial);
    bucket_k<<<6250, 256, 0, stream>>>(src, dst, rank, rowptr, ssrc);

    const float betas[4] = { logf(1.5f), logf(1.25f), logf(7.f / 6.f), logf(1.125f) };

    // x0 residual = h0 (same values); h0 preserved, hA/hB ping-pong
    layer_k<<<LBLK, 256, 0, stream>>>(h0, h0, rowptr, ssrc, convW + 0 * 2304, betas[0], hB);
    layer_k<<<LBLK, 256, 0, stream>>>(hB, h0, rowptr, ssrc, convW + 1 * 2304, betas[1], hA);
    layer_k<<<LBLK, 256, 0, stream>>>(hA, h0, rowptr, ssrc, convW + 2 * 2304, betas[2], hB);
    layer_k<<<LBLK, 256, 0, stream>>>(hB, h0, rowptr, ssrc, convW + 3 * 2304, betas[3], hA);
    final_k<<<6250, 256, 0, stream>>>(hA, W1, b1, out);
}